// Round 1
// baseline (1179.609 us; speedup 1.0000x reference)
//
#include <hip/hip_runtime.h>
#include <cmath>

constexpr int kLevels = 16;
constexpr unsigned kLog2T = 19;
constexpr unsigned kT = 1u << kLog2T;
constexpr unsigned kMask = kT - 1u;
constexpr unsigned P1 = 2654435761u;
constexpr unsigned P2 = 805459861u;

struct LevelParams {
  float scale[kLevels];   // res * 0.5  (u = (x+1) * res/2)
  float resm1[kLevels];   // res - 1    (clip bound for floor(u))
};

__global__ __launch_bounds__(256) void hash_embed_kernel(
    const float* __restrict__ x,
    const float* __restrict__ tables,
    float* __restrict__ out,
    LevelParams lp, int B)
{
  int b = blockIdx.x * 256 + threadIdx.x;
  if (b >= B) return;

  const float px = x[3 * b + 0];
  const float py = x[3 * b + 1];
  const float pz = x[3 * b + 2];
  float* orow = out + (size_t)b * (2 * kLevels);

  const float2* tbl = (const float2*)tables;
  for (int l = 0; l < kLevels; ++l, tbl += kT) {
    const float s   = lp.scale[l];
    const float rm1 = lp.resm1[l];

    // continuous grid coords; u in [0, res]
    const float ux = (px + 1.0f) * s;
    const float uy = (py + 1.0f) * s;
    const float uz = (pz + 1.0f) * s;

    const float fx = fminf(fmaxf(floorf(ux), 0.0f), rm1);
    const float fy = fminf(fmaxf(floorf(uy), 0.0f), rm1);
    const float fz = fminf(fmaxf(floorf(uz), 0.0f), rm1);

    const float tx = ux - fx;
    const float ty = uy - fy;
    const float tz = uz - fz;

    const unsigned ix = (unsigned)fx;
    const unsigned iy = (unsigned)fy;
    const unsigned iz = (unsigned)fz;

    // spatial hash: h = (ix+ox)*1 ^ (iy+oy)*P1 ^ (iz+oz)*P2, uint32 wraparound.
    // (i+1)*P == i*P + P mod 2^32  -> only 2 mults per level.
    const unsigned ax0 = ix;
    const unsigned ax1 = ix + 1u;
    const unsigned by0 = iy * P1;
    const unsigned by1 = by0 + P1;
    const unsigned cz0 = iz * P2;
    const unsigned cz1 = cz0 + P2;

    const unsigned bc00 = by0 ^ cz0;   // oy=0, oz=0
    const unsigned bc10 = by1 ^ cz0;   // oy=1, oz=0
    const unsigned bc01 = by0 ^ cz1;   // oy=0, oz=1
    const unsigned bc11 = by1 ^ cz1;   // oy=1, oz=1

    // 8 independent gathers (float2 = 8B each), issued back-to-back
    const float2 e000 = tbl[(ax0 ^ bc00) & kMask];
    const float2 e100 = tbl[(ax1 ^ bc00) & kMask];
    const float2 e010 = tbl[(ax0 ^ bc10) & kMask];
    const float2 e110 = tbl[(ax1 ^ bc10) & kMask];
    const float2 e001 = tbl[(ax0 ^ bc01) & kMask];
    const float2 e101 = tbl[(ax1 ^ bc01) & kMask];
    const float2 e011 = tbl[(ax0 ^ bc11) & kMask];
    const float2 e111 = tbl[(ax1 ^ bc11) & kMask];

    // trilinear weights
    const float wx1 = tx, wx0 = 1.0f - tx;
    const float wy1 = ty, wy0 = 1.0f - ty;
    const float wz1 = tz, wz0 = 1.0f - tz;

    const float wyz00 = wy0 * wz0;
    const float wyz10 = wy1 * wz0;
    const float wyz01 = wy0 * wz1;
    const float wyz11 = wy1 * wz1;

    const float w000 = wx0 * wyz00, w100 = wx1 * wyz00;
    const float w010 = wx0 * wyz10, w110 = wx1 * wyz10;
    const float w001 = wx0 * wyz01, w101 = wx1 * wyz01;
    const float w011 = wx0 * wyz11, w111 = wx1 * wyz11;

    float f0 = w000 * e000.x;
    float f1 = w000 * e000.y;
    f0 = fmaf(w100, e100.x, f0);  f1 = fmaf(w100, e100.y, f1);
    f0 = fmaf(w010, e010.x, f0);  f1 = fmaf(w010, e010.y, f1);
    f0 = fmaf(w110, e110.x, f0);  f1 = fmaf(w110, e110.y, f1);
    f0 = fmaf(w001, e001.x, f0);  f1 = fmaf(w001, e001.y, f1);
    f0 = fmaf(w101, e101.x, f0);  f1 = fmaf(w101, e101.y, f1);
    f0 = fmaf(w011, e011.x, f0);  f1 = fmaf(w011, e011.y, f1);
    f0 = fmaf(w111, e111.x, f0);  f1 = fmaf(w111, e111.y, f1);

    orow[2 * l + 0] = f0;
    orow[2 * l + 1] = f1;
  }
}

extern "C" void kernel_launch(void* const* d_in, const int* in_sizes, int n_in,
                              void* d_out, int out_size, void* d_ws, size_t ws_size,
                              hipStream_t stream) {
  const float* x      = (const float*)d_in[0];
  const float* tables = (const float*)d_in[1];
  float* out          = (float*)d_out;
  const int B = in_sizes[0] / 3;

  // Replicate numpy's double-precision resolution computation bit-exactly:
  // _FACTOR = exp((log(512) - log(16)) / 15); res_i = int(floor(16 * _FACTOR**i))
  // (same glibc exp/log/pow as the harness's numpy on this container; the
  //  i = 3,6,9,12,15 cases land within ulps of exact powers of two, so we must
  //  NOT hardcode a guessed table.)
  LevelParams lp;
  const double factor = exp((log(512.0) - log(16.0)) / 15.0);
  for (int i = 0; i < kLevels; ++i) {
    const int res = (int)floor(16.0 * pow(factor, (double)i));
    lp.scale[i] = (float)res * 0.5f;
    lp.resm1[i] = (float)(res - 1);
  }

  const int block = 256;
  const int grid = (B + block - 1) / block;
  hipLaunchKernelGGL(hash_embed_kernel, dim3(grid), dim3(block), 0, stream,
                     x, tables, out, lp, B);
}